// Round 1
// 2296.280 us; speedup vs baseline: 1.0324x; 1.0324x over previous
//
#include <hip/hip_runtime.h>
#include <hip/hip_bf16.h>
#include <stdint.h>

// SparseMPNNLayer: bipartite MPNN, H=64. Round 3: kill the 8x input re-gather.
//  edge MLP 192->128->64 restructured as two half-hidden passes (h[64] in regs),
//  so each edge's x row is gathered 2x (was 8x). node MLP 128->64->64 keeps the
//  full h[64] in regs -> 1x load (was 4x). DT (f32/bf16 storage) and PHASE are
//  now runtime-uniform branches instead of dead-launched template pairs.
//  Transpose LDS shrunk to [64][17] chunked so LDS never caps occupancy.

__device__ __forceinline__ void unpack2(unsigned int u, float& a, float& b) {
    union { unsigned int i; float f; } x, y;
    x.i = u << 16;          // low half = element 0
    y.i = u & 0xffff0000u;  // high half = element 1
    a = x.f; b = y.f;
}

__device__ __forceinline__ void load16bf(const __hip_bfloat16* __restrict__ p, float* xr) {
    const uint4* q = reinterpret_cast<const uint4*>(p);
    uint4 a = q[0];
    uint4 b = q[1];
    unpack2(a.x, xr[0], xr[1]);  unpack2(a.y, xr[2], xr[3]);
    unpack2(a.z, xr[4], xr[5]);  unpack2(a.w, xr[6], xr[7]);
    unpack2(b.x, xr[8], xr[9]);  unpack2(b.y, xr[10], xr[11]);
    unpack2(b.z, xr[12], xr[13]); unpack2(b.w, xr[14], xr[15]);
}

__device__ __forceinline__ void load16f(const float* __restrict__ p, float* xr) {
    const float4* q = reinterpret_cast<const float4*>(p);
#pragma unroll
    for (int i = 0; i < 4; ++i) {
        float4 v = q[i];
        xr[4*i+0] = v.x; xr[4*i+1] = v.y; xr[4*i+2] = v.z; xr[4*i+3] = v.w;
    }
}

__device__ __forceinline__ void load16(const void* base, size_t off, int isbf, float* xr) {
    if (isbf) load16bf((const __hip_bfloat16*)base + off, xr);
    else      load16f((const float*)base + off, xr);
}

// Classify storage of h_v: packed-bf16 pairs have a bf16 exponent field in the
// low 16 bits of each u32 (~99.7% in [100,140] for N(0,1)); f32 mantissa bits
// hit that window ~16% of the time.
__global__ void detect_kernel(const unsigned int* __restrict__ hv, int* __restrict__ flag) {
    __shared__ int cnt;
    if (threadIdx.x == 0) cnt = 0;
    __syncthreads();
    unsigned int w = hv[threadIdx.x];
    int ef = (w >> 7) & 0xff;
    if (ef >= 100 && ef <= 140) atomicAdd(&cnt, 1);
    __syncthreads();
    if (threadIdx.x == 0) flag[0] = (cnt > 256) ? 1 : 0;
}

struct WArgs {
    const void* p[16];
    int off[16];
    int cnt[16];
};

__global__ void cvt_all(WArgs wa, float* __restrict__ wf, const int* __restrict__ gflag) {
    const int isbf = gflag[0];
    const int t = blockIdx.y;
    const int i = blockIdx.x * 256 + threadIdx.x;
    if (i >= wa.cnt[t]) return;
    wf[wa.off[t] + i] = isbf ? __bfloat162float(((const __hip_bfloat16*)wa.p[t])[i])
                             : ((const float*)wa.p[t])[i];
}

__global__ void deg_kernel(const int* __restrict__ src, float* __restrict__ degv, int E) {
    int e = blockIdx.x * 256 + threadIdx.x;
    if (e < E) atomicAdd(&degv[src[e]], 1.0f);
}

// Edge MLP: K=192 -> 128 (relu) -> 64, scatter-add into accum rows.
// ph3==0: x = [A=h_v[src] | B=h_u[dst] | e_feat], scatter row = dst
// ph3==1: x = [A=h_u_out[dst] | B=h_v[src] | e_feat], scatter row = src
// A_f/A_b are the f32/bf16 interpretations of A (differ only for phase 3).
__global__ __launch_bounds__(64)
void edge_mlp(const void* __restrict__ A_f, const void* __restrict__ A_b,
              const void* __restrict__ B,
              const void* __restrict__ Efeat,
              const int* __restrict__ src_idx, const int* __restrict__ dst_idx,
              const int* __restrict__ gflag,
              const float* __restrict__ w1, const float* __restrict__ b1,
              const float* __restrict__ w2, const float* __restrict__ b2,
              float* __restrict__ accum, int E, int ph3) {
    const int isbf = gflag[0];
    const void* A = isbf ? A_b : A_f;
    __shared__ float sm[64][17];
    __shared__ int rowS[64];

    const int lane = threadIdx.x;
    const int base = blockIdx.x * 64;
    const int cnt = min(64, E - base);
    const int eSafe = base + ((lane < cnt) ? lane : 0);
    const int s = src_idx[eSafe];
    const int d = dst_idx[eSafe];
    rowS[lane] = ph3 ? s : d;

    const size_t offA = (size_t)(ph3 ? d : s) * 64;
    const size_t offB = (size_t)(ph3 ? s : d) * 64;
    const size_t offE = (size_t)eSafe * 64;

    float acc[64];
#pragma unroll
    for (int o = 0; o < 64; ++o) acc[o] = b2[o];

    // Two half-hidden passes: h[64] lives entirely in registers, so the
    // 192-wide input row is gathered exactly twice (was 8x).
#pragma unroll 1
    for (int half = 0; half < 2; ++half) {
        const int hb = half << 6;
        float h[64];
#pragma unroll
        for (int j = 0; j < 64; ++j) h[j] = b1[hb + j];
#pragma unroll 1
        for (int kc = 0; kc < 12; ++kc) {       // K 192 = 12 x 16
            float xr[16];
            if (kc < 4)      load16(A, offA + kc * 16, isbf, xr);
            else if (kc < 8) load16(B, offB + (kc - 4) * 16, isbf, xr);
            else             load16(Efeat, offE + (kc - 8) * 16, isbf, xr);
            const float* wrow = w1 + (size_t)(kc * 16) * 128 + hb;
#pragma unroll
            for (int k = 0; k < 16; ++k)
#pragma unroll
                for (int j = 0; j < 64; ++j)
                    h[j] = fmaf(xr[k], wrow[k * 128 + j], h[j]);
        }
#pragma unroll
        for (int j = 0; j < 64; ++j) h[j] = fmaxf(h[j], 0.0f);
        const float* w2h = w2 + (size_t)hb * 64;
#pragma unroll
        for (int j = 0; j < 64; ++j)
#pragma unroll
            for (int o = 0; o < 64; ++o)
                acc[o] = fmaf(h[j], w2h[j * 64 + o], acc[o]);
    }

    // Chunked transpose through small LDS -> coalesced wave-wide atomic rows.
    const int r4 = lane >> 4;
    const int c16 = lane & 15;
#pragma unroll
    for (int oc = 0; oc < 4; ++oc) {
        __syncthreads();
#pragma unroll
        for (int j = 0; j < 16; ++j) sm[lane][j] = acc[oc * 16 + j];
        __syncthreads();
        for (int i = 0; i < 64; i += 4) {
            const int e = i + r4;
            if (e < cnt)
                atomicAdd(&accum[(size_t)rowS[e] * 64 + oc * 16 + c16], sm[e][c16]);
        }
    }
}

// Node MLP: K=128 -> 64 (relu) -> 64. Full h[64] in regs -> x loaded once.
// ph4==0: x = [h_u | m_u/S]          -> h_u_out region of d_out
// ph4==1: x = [h_v | m_v/max(deg,1)] -> h_v_out region of d_out
__global__ __launch_bounds__(256)
void node_mlp(const void* __restrict__ hin,
              const float* __restrict__ m,
              const float* __restrict__ degv,
              const int* __restrict__ Sptr,
              const int* __restrict__ gflag,
              const float* __restrict__ w1, const float* __restrict__ b1,
              const float* __restrict__ w2, const float* __restrict__ b2,
              void* __restrict__ out_f, void* __restrict__ out_b,
              int N, int ph4) {
    const int isbf = gflag[0];
    const int n = blockIdx.x * 256 + threadIdx.x;
    if (n >= N) return;
    const float scale = ph4 ? (1.0f / fmaxf(degv[n], 1.0f))
                            : (1.0f / (float)Sptr[0]);
    const size_t offH = (size_t)n * 64;
    const float* pm = m + offH;

    float h[64];
#pragma unroll
    for (int j = 0; j < 64; ++j) h[j] = b1[j];
#pragma unroll 1
    for (int kc = 0; kc < 8; ++kc) {            // K 128 = 8 x 16
        float xr[16];
        if (kc < 4) {
            load16(hin, offH + kc * 16, isbf, xr);
        } else {
            load16f(pm + (kc - 4) * 16, xr);
#pragma unroll
            for (int k = 0; k < 16; ++k) xr[k] *= scale;
        }
#pragma unroll
        for (int k = 0; k < 16; ++k)
#pragma unroll
            for (int j = 0; j < 64; ++j)
                h[j] = fmaf(xr[k], w1[(kc * 16 + k) * 64 + j], h[j]);
    }
#pragma unroll
    for (int j = 0; j < 64; ++j) h[j] = fmaxf(h[j], 0.0f);

    float acc[64];
#pragma unroll
    for (int o = 0; o < 64; ++o) acc[o] = b2[o];
#pragma unroll
    for (int j = 0; j < 64; ++j)
#pragma unroll
        for (int o = 0; o < 64; ++o)
            acc[o] = fmaf(h[j], w2[j * 64 + o], acc[o]);

    if (isbf) {
        unsigned int ob[32];
#pragma unroll
        for (int i = 0; i < 32; ++i) {
            __hip_bfloat162 p2 = __float22bfloat162_rn(make_float2(acc[2 * i], acc[2 * i + 1]));
            ob[i] = *reinterpret_cast<unsigned int*>(&p2);
        }
        uint4* qo = reinterpret_cast<uint4*>((__hip_bfloat16*)out_b + offH);
#pragma unroll
        for (int i = 0; i < 8; ++i) qo[i] = make_uint4(ob[4*i], ob[4*i+1], ob[4*i+2], ob[4*i+3]);
    } else {
        float4* qf = reinterpret_cast<float4*>((float*)out_f + offH);
#pragma unroll
        for (int i = 0; i < 16; ++i) qf[i] = make_float4(acc[4*i], acc[4*i+1], acc[4*i+2], acc[4*i+3]);
    }
}

extern "C" void kernel_launch(void* const* d_in, const int* in_sizes, int n_in,
                              void* d_out, int out_size, void* d_ws, size_t ws_size,
                              hipStream_t stream) {
    const void* h_v    = d_in[0];
    const void* h_u    = d_in[1];
    const void* e_feat = d_in[2];
    const int* eidx = (const int*)d_in[3];
    const int* Sptr = (const int*)d_in[4];

    const int NV_ = in_sizes[0] / 64;
    const int NU_ = in_sizes[1] / 64;
    const int E_  = in_sizes[2] / 64;
    const int* src = eidx;        // edge_index row 0 (indexes h_v)
    const int* dst = eidx + E_;   // edge_index row 1 (indexes h_u)

    const int maxN = (NV_ > NU_) ? NV_ : NU_;
    // ws layout: flag (64B) | mbuf[maxN*64] f32 | degv[NV] f32 | wf (f32 weights)
    int*   flag = (int*)d_ws;
    float* mbuf = (float*)((char*)d_ws + 64);
    float* degv = mbuf + (size_t)maxN * 64;
    float* wf   = degv + NV_;

    WArgs wa;
    int accum = 0;
    int maxCnt = 0;
    for (int i = 0; i < 16; ++i) {
        wa.p[i] = d_in[5 + i];
        wa.off[i] = accum;
        wa.cnt[i] = in_sizes[5 + i];
        accum += in_sizes[5 + i];
        if (in_sizes[5 + i] > maxCnt) maxCnt = in_sizes[5 + i];
    }

    detect_kernel<<<1, 512, 0, stream>>>((const unsigned int*)h_v, flag);

    dim3 cg((maxCnt + 255) / 256, 16);
    cvt_all<<<cg, 256, 0, stream>>>(wa, wf, flag);

    // Output regions per dtype interpretation.
    void* out_hv_f = d_out;
    void* out_hu_f = (void*)((float*)d_out + (size_t)NV_ * 64);
    void* out_hu_b = (void*)((__hip_bfloat16*)d_out + (size_t)NV_ * 64);

    hipMemsetAsync(mbuf, 0, (size_t)maxN * 64 * sizeof(float), stream);

    const int egrid = (E_ + 63) / 64;
    // phase 1: A=h_v (same ptr for both dtypes), B=h_u, scatter by dst
    edge_mlp<<<egrid, 64, 0, stream>>>(h_v, h_v, h_u, e_feat, src, dst, flag,
        wf + wa.off[0], wf + wa.off[1], wf + wa.off[2], wf + wa.off[3], mbuf, E_, 0);

    const int ngridU = (NU_ + 255) / 256;
    node_mlp<<<ngridU, 256, 0, stream>>>(h_u, mbuf, nullptr, Sptr, flag,
        wf + wa.off[4], wf + wa.off[5], wf + wa.off[6], wf + wa.off[7],
        out_hu_f, out_hu_b, NU_, 0);

    hipMemsetAsync(mbuf, 0, (size_t)maxN * 64 * sizeof(float), stream);
    hipMemsetAsync(degv, 0, (size_t)NV_ * sizeof(float), stream);

    deg_kernel<<<(E_ + 255) / 256, 256, 0, stream>>>(src, degv, E_);

    // phase 3: A=h_u_out (dtype-dependent region of d_out), B=h_v, scatter by src
    edge_mlp<<<egrid, 64, 0, stream>>>(out_hu_f, out_hu_b, h_v, e_feat, src, dst, flag,
        wf + wa.off[8], wf + wa.off[9], wf + wa.off[10], wf + wa.off[11], mbuf, E_, 1);

    const int ngridV = (NV_ + 255) / 256;
    node_mlp<<<ngridV, 256, 0, stream>>>(h_v, mbuf, degv, Sptr, flag,
        wf + wa.off[12], wf + wa.off[13], wf + wa.off[14], wf + wa.off[15],
        out_hv_f, d_out, NV_, 1);
}